// Round 1
// baseline (339.476 us; speedup 1.0000x reference)
//
#include <hip/hip_runtime.h>
#include <math.h>

// Problem constants (from reference): T=4, V=2, L=3, N=4000, D=256, TEMP=0.5
#define DD 256
#define NV 2
#define NL 3
#define NNODE 4000
// Row table: B-rows (anchors at all 6 (x,y)) then C-rows (cross negatives).
//   B: t0 [0,3600) S=100 | t1 [3600,7200) | t2 [7200,7920) S=20 | t3 [7920,8640)
//   C: t0 [8640,9540) K=50 | t1 [9540,10440) | t2 [10440,10620) K=10 | t3 [10620,10800)
#define NROWS_B 8640
#define NROWS 10800
#define ACC_OFF (10800L * 256)  // float offset in ws of accumulators
#define NANCH 1440              // total anchors = 2*600 + 2*120

__device__ __forceinline__ int tb_B(int t) { return (t < 2) ? t * 3600 : 7200 + (t - 2) * 720; }
__device__ __forceinline__ int tb_C(int t) { return (t < 2) ? t * 900 : 1800 + (t - 2) * 180; }
__device__ __forceinline__ int anch_base(int t, int vl) {
  return ((t < 2) ? t * 600 : 1200 + (t - 2) * 120) + vl * ((t < 2) ? 100 : 20);
}
// ws row id of anchor z(t,v,l,s) = B row with xy == (v,l)
__device__ __forceinline__ int zrow_id(int t, int v, int l, int s, int S) {
  int vl = v * NL + l;
  return tb_B(t) + ((vl * NV + v) * NL + l) * S + s;
}

// Map flat row id u -> source offset (floats) in E. Uniform across block.
__device__ __forceinline__ long row_src(int u, const int* __restrict__ ip,
                                        const int* __restrict__ ir,
                                        const int* __restrict__ npg,
                                        const int* __restrict__ nrg) {
  int t, x, y, node;
  if (u < NROWS_B) {
    int S, u2;
    if (u < 7200) { t = u / 3600; u2 = u - t * 3600; S = 100; }
    else { int w = u - 7200; t = 2 + w / 720; u2 = w % 720; S = 20; }
    int s = u2 % S; int t1 = u2 / S;
    int l = t1 % NL; int t2 = t1 / NL;
    int v = t2 % NV; int xy = t2 / NV;
    x = xy / NL; y = xy % NL;
    if (t < 2) node = ip[((t * NV + v) * NL + l) * 100 + s];
    else       node = ir[(((t - 2) * NV + v) * NL + l) * 20 + s];
  } else {
    int w = u - NROWS_B;
    int K, u2;
    if (w < 1800) { t = w / 900; u2 = w % 900; K = 50; }
    else { int w2 = w - 1800; t = 2 + w2 / 180; u2 = w2 % 180; K = 10; }
    int k = u2 % K; int t1 = u2 / K;
    int l = t1 % NL; int t2 = t1 / NL;
    int v = t2 % NV; int o = t2 / NV;
    if (t < 2) node = npg[(((t * NV + v) * NL + l) * 3 + o) * 50 + k];
    else       node = nrg[((((t - 2) * NV + v) * NL + l) * 3 + o) * 10 + k];
    int ot = (o < t) ? o : o + 1;  // others[o] for type t
    t = ot; x = v; y = l;
  }
  return ((((long)t * NV + x) * NL + y) * NNODE + node) * DD;
}

// K1: gather 16 rows/block, project (Linear-ReLU-Linear), L2-normalize, store to ws.
// thread j owns output column j; acc[16] register-blocks rows so each W row is
// loaded from L2 once per 16 rows.
__global__ __launch_bounds__(256) void k_proj(const float* __restrict__ E,
                                              const float* __restrict__ W1,
                                              const float* __restrict__ b1,
                                              const float* __restrict__ W2,
                                              const float* __restrict__ b2,
                                              const int* __restrict__ ip,
                                              const int* __restrict__ ir,
                                              const int* __restrict__ npg,
                                              const int* __restrict__ nrg,
                                              float* __restrict__ ws) {
  __shared__ float X[16][DD];
  __shared__ float H[16][DD];
  __shared__ float wsum[4][16];
  const int tid = threadIdx.x;
  const int u0 = blockIdx.x * 16;

  for (int r = 0; r < 16; ++r) {
    long src = row_src(u0 + r, ip, ir, npg, nrg);  // uniform -> scalar loads
    X[r][tid] = E[src + tid];                      // coalesced
  }
  __syncthreads();

  float acc[16];
  // stage 1: h[r][j] = relu(b1[j] + sum_d X[r][d] * W1[j][d])
  {
    float bv = b1[tid];
#pragma unroll
    for (int r = 0; r < 16; ++r) acc[r] = bv;
    const float4* Wr = (const float4*)(W1 + (long)tid * DD);
    for (int c = 0; c < 64; ++c) {
      float4 w = Wr[c];
#pragma unroll
      for (int r = 0; r < 16; ++r) {
        float4 xv = *(const float4*)(&X[r][c * 4]);  // LDS broadcast
        acc[r] = fmaf(w.x, xv.x, acc[r]);
        acc[r] = fmaf(w.y, xv.y, acc[r]);
        acc[r] = fmaf(w.z, xv.z, acc[r]);
        acc[r] = fmaf(w.w, xv.w, acc[r]);
      }
    }
#pragma unroll
    for (int r = 0; r < 16; ++r) H[r][tid] = fmaxf(acc[r], 0.0f);
  }
  __syncthreads();
  // stage 2: z[r][j] = b2[j] + sum_d H[r][d] * W2[j][d]
  {
    float bv = b2[tid];
#pragma unroll
    for (int r = 0; r < 16; ++r) acc[r] = bv;
    const float4* Wr = (const float4*)(W2 + (long)tid * DD);
    for (int c = 0; c < 64; ++c) {
      float4 w = Wr[c];
#pragma unroll
      for (int r = 0; r < 16; ++r) {
        float4 xv = *(const float4*)(&H[r][c * 4]);
        acc[r] = fmaf(w.x, xv.x, acc[r]);
        acc[r] = fmaf(w.y, xv.y, acc[r]);
        acc[r] = fmaf(w.z, xv.z, acc[r]);
        acc[r] = fmaf(w.w, xv.w, acc[r]);
      }
    }
  }
  // norms: wave shfl-xor butterfly over the 64 lanes, then combine 4 waves
  float ss[16];
#pragma unroll
  for (int r = 0; r < 16; ++r) ss[r] = acc[r] * acc[r];
  for (int off = 32; off > 0; off >>= 1) {
#pragma unroll
    for (int r = 0; r < 16; ++r) ss[r] += __shfl_xor(ss[r], off, 64);
  }
  const int wave = tid >> 6, lane = tid & 63;
  if (lane == 0) {
#pragma unroll
    for (int r = 0; r < 16; ++r) wsum[wave][r] = ss[r];
  }
  __syncthreads();
#pragma unroll
  for (int r = 0; r < 16; ++r) {
    float tot = wsum[0][r] + wsum[1][r] + wsum[2][r] + wsum[3][r];
    float sc = 1.0f / fmaxf(sqrtf(tot), 1e-12f);
    ws[(long)(u0 + r) * DD + tid] = acc[r] * sc;  // coalesced per r
  }
}

// K2: per (t,v,l): pos[s] = sum over xy != (v,l) of exp(2*dot(z_s, B[xy][v][l][s])).
// Also zeroes neg accumulators (runs before K3 on the stream).
__global__ __launch_bounds__(256) void k_pos(float* __restrict__ ws) {
  __shared__ float posL[100];
  const int b = blockIdx.x;
  const int t = b / 6, vl = b % 6, v = vl / NL, l = vl % NL;
  const int S = (t < 2) ? 100 : 20;
  const int tid = threadIdx.x;
  for (int i = tid; i < S; i += 256) posL[i] = 0.0f;
  __syncthreads();
  const int npairs = S * 6;
  for (int p = tid; p < npairs; p += 256) {
    int s = p / 6, xy = p % 6;
    if (xy == vl) continue;  // same_vl masked to 0
    long zr = (long)zrow_id(t, v, l, s, S) * DD;
    long pr = (long)(tb_B(t) + ((xy * NV + v) * NL + l) * S + s) * DD;
    const float4* za = (const float4*)(ws + zr);
    const float4* pa = (const float4*)(ws + pr);
    float d = 0.0f;
    for (int c = 0; c < 64; ++c) {
      float4 a = za[c]; float4 bb = pa[c];
      d = fmaf(a.x, bb.x, d); d = fmaf(a.y, bb.y, d);
      d = fmaf(a.z, bb.z, d); d = fmaf(a.w, bb.w, d);
    }
    atomicAdd(&posL[s], expf(2.0f * d));
  }
  __syncthreads();
  const int ab = anch_base(t, vl);
  for (int s = tid; s < S; s += 256) {
    ws[ACC_OFF + ab + s] = posL[s];           // pos
    ws[ACC_OFF + NANCH + ab + s] = 0.0f;      // zero neg for K3's atomics
  }
}

// K3: neg[s] = sum over in-type (t'!=s) + cross-type partners of exp(2*dot).
// Per block: one (t,v,l) x partner-chunk(64); LDS-staged tiles, 7x4 register tile.
__global__ __launch_bounds__(256) void k_neg(float* __restrict__ ws) {
  __shared__ float Zt[112][33];  // padded rows (a up to 111) + bank pad
  __shared__ float Pt[64][33];
  const int b = blockIdx.x;
  int t, vl, c;
  if (b < 48) { t = b / 24; int r = b % 24; vl = r / 4; c = r % 4; }
  else { int q = b - 48; t = 2 + q / 6; vl = q % 6; c = 0; }
  const int v = vl / NL, l = vl % NL;
  const int S = (t < 2) ? 100 : 20, K = (t < 2) ? 50 : 10;
  const int Ptot = S + 3 * K;          // 250 or 50
  const int q0 = c * 64;
  const int pn = min(64, Ptot - q0);
  const int tid = threadIdx.x;
  const int tx = tid & 15, ty = tid >> 4;

  float acc[7][4];
#pragma unroll
  for (int i = 0; i < 7; ++i)
#pragma unroll
    for (int j = 0; j < 4; ++j) acc[i][j] = 0.0f;

  for (int kc = 0; kc < DD; kc += 32) {
    __syncthreads();
    for (int e = tid; e < 112 * 32; e += 256) {
      int a = e >> 5, col = e & 31;
      float val = 0.0f;
      if (a < S) val = ws[(long)zrow_id(t, v, l, a, S) * DD + kc + col];
      Zt[a][col] = val;
    }
    for (int e = tid; e < 64 * 32; e += 256) {
      int q = e >> 5, col = e & 31;
      float val = 0.0f;
      if (q < pn) {
        int qg = q0 + q;
        long row;
        if (qg < S) row = zrow_id(t, v, l, qg, S);  // in-type negatives = anchors
        else {
          int q2 = qg - S; int o = q2 / K, k2 = q2 % K;
          row = NROWS_B + tb_C(t) + ((o * NV + v) * NL + l) * K + k2;
        }
        val = ws[row * DD + kc + col];
      }
      Pt[q][col] = val;
    }
    __syncthreads();
    for (int k = 0; k < 32; ++k) {
      float pb[4];
#pragma unroll
      for (int j = 0; j < 4; ++j) pb[j] = Pt[tx * 4 + j][k];
#pragma unroll
      for (int i = 0; i < 7; ++i) {
        float za = Zt[ty + 16 * i][k];
#pragma unroll
        for (int j = 0; j < 4; ++j) acc[i][j] = fmaf(za, pb[j], acc[i][j]);
      }
    }
  }
  // epilogue: exp, mask diagonal of in-type block, reduce over tx (16-lane groups)
#pragma unroll
  for (int i = 0; i < 7; ++i) {
    int a = ty + 16 * i;
    float sum = 0.0f;
    if (a < S) {
#pragma unroll
      for (int j = 0; j < 4; ++j) {
        int qg = q0 + tx * 4 + j;
        if (qg < Ptot && !(qg < S && qg == a)) sum += expf(2.0f * acc[i][j]);
      }
    }
    for (int o = 8; o > 0; o >>= 1) sum += __shfl_xor(sum, o, 16);
    if (a < S && tx == 0)
      atomicAdd(&ws[ACC_OFF + NANCH + anch_base(t, vl) + a], sum);
  }
}

// K4: loss = mean over 1440 anchors of -log(pos/(pos+neg))
__global__ __launch_bounds__(256) void k_fin(const float* __restrict__ ws,
                                             float* __restrict__ out) {
  __shared__ float red[256];
  const int tid = threadIdx.x;
  float sum = 0.0f;
  for (int i = tid; i < NANCH; i += 256) {
    float p = ws[ACC_OFF + i];
    float n = ws[ACC_OFF + NANCH + i];
    sum += -logf(p / (p + n));
  }
  red[tid] = sum;
  __syncthreads();
  for (int s = 128; s > 0; s >>= 1) {
    if (tid < s) red[tid] += red[tid + s];
    __syncthreads();
  }
  if (tid == 0) out[0] = red[0] / (float)NANCH;
}

extern "C" void kernel_launch(void* const* d_in, const int* in_sizes, int n_in,
                              void* d_out, int out_size, void* d_ws, size_t ws_size,
                              hipStream_t stream) {
  const float* E  = (const float*)d_in[0];
  const float* W1 = (const float*)d_in[1];
  const float* b1 = (const float*)d_in[2];
  const float* W2 = (const float*)d_in[3];
  const float* b2 = (const float*)d_in[4];
  const int* ip  = (const int*)d_in[5];
  const int* ir  = (const int*)d_in[6];
  const int* npg = (const int*)d_in[7];
  const int* nrg = (const int*)d_in[8];
  float* ws = (float*)d_ws;   // needs ~11.1 MB: 10800 rows*256 + 2*1440 accumulators
  float* out = (float*)d_out;

  hipLaunchKernelGGL(k_proj, dim3(NROWS / 16), dim3(256), 0, stream,
                     E, W1, b1, W2, b2, ip, ir, npg, nrg, ws);
  hipLaunchKernelGGL(k_pos, dim3(24), dim3(256), 0, stream, ws);
  hipLaunchKernelGGL(k_neg, dim3(60), dim3(256), 0, stream, ws);
  hipLaunchKernelGGL(k_fin, dim3(1), dim3(256), 0, stream, ws, out);
}